// Round 6
// baseline (344.001 us; speedup 1.0000x reference)
//
#include <hip/hip_runtime.h>
#include <hip/hip_bf16.h>
#include <math.h>

typedef float f32x4  __attribute__((ext_vector_type(4)));
typedef float f32x16 __attribute__((ext_vector_type(16)));
typedef short s16x8  __attribute__((ext_vector_type(8)));
typedef short s16x4  __attribute__((ext_vector_type(4)));

__device__ inline short f2bf(float f) {
    union { __hip_bfloat16 h; short s; } u;
    u.h = __float2bfloat16(f);
    return u.s;
}

__device__ inline s16x8 f32x8_to_bf16x8(f32x4 a, f32x4 b) {
    s16x8 o;
    union { __hip_bfloat162 h; short2 s; } u;
    u.h = __float22bfloat162_rn(make_float2(a[0], a[1])); o[0] = u.s.x; o[1] = u.s.y;
    u.h = __float22bfloat162_rn(make_float2(a[2], a[3])); o[2] = u.s.x; o[3] = u.s.y;
    u.h = __float22bfloat162_rn(make_float2(b[0], b[1])); o[4] = u.s.x; o[5] = u.s.y;
    u.h = __float22bfloat162_rn(make_float2(b[2], b[3])); o[6] = u.s.x; o[7] = u.s.y;
    return o;
}

// ---------------------------------------------------------------------------
// Kernel 1: pack weights -> WallT[n][k] bf16, n in [0,384) = f|g|h cols
// ---------------------------------------------------------------------------
__global__ __launch_bounds__(256) void wconv_kernel(
    const float* __restrict__ Wf, const float* __restrict__ Wg,
    const float* __restrict__ Wh, short* __restrict__ WallT)
{
    int t = blockIdx.x * 256 + threadIdx.x;
    int n = t >> 8;
    int k = t & 255;
    float v;
    if (n < 64)       v = Wf[k * 64 + n];
    else if (n < 128) v = Wg[k * 64 + (n - 64)];
    else              v = Wh[k * 256 + (n - 128)];
    WallT[n * 256 + k] = f2bf(v);
}

// ---------------------------------------------------------------------------
// Kernel 2: projections, LDS-free, kk-outer (6 independent MFMA chains).
// Grid 1024 x 256; 16 px/block. Outputs retiled for attn's access pattern:
//   Kp[b][key][64]  (f)          -- contiguous 128B rows
//   Qp[b][q][64]    (g)
//   Vp[b][panel=key>>6][ch][key&63]  -- V^T in 64-key panels: attn's V-tile
//                                       read is one contiguous 4KB block/ct
// ---------------------------------------------------------------------------
__global__ __launch_bounds__(256) void proj_kernel(
    const float* __restrict__ x, const short* __restrict__ WallT,
    const float* __restrict__ bfv, const float* __restrict__ bgv,
    const float* __restrict__ bhv,
    short* __restrict__ Kp, short* __restrict__ Qp, short* __restrict__ Vp)
{
    const int tid  = threadIdx.x;
    const int lane = tid & 63, w = tid >> 6;
    const int quad = lane >> 4, l15 = lane & 15;
    const int p0 = blockIdx.x * 16;

    s16x8 xf[8];
    {
        const float* xrow = x + (size_t)(p0 + l15) * 256 + quad * 8;
        for (int kk = 0; kk < 8; ++kk) {
            f32x4 a = *(const f32x4*)(xrow + kk * 32);
            f32x4 c = *(const f32x4*)(xrow + kk * 32 + 4);
            xf[kk] = f32x8_to_bf16x8(a, c);
        }
    }

    f32x4 acc[6];
    const f32x4 zac = {0.f, 0.f, 0.f, 0.f};
    for (int i = 0; i < 6; ++i) acc[i] = zac;

    const short* w1a = WallT + (size_t)((w * 2 + 0) * 16 + l15) * 256 + quad * 8;
    const short* w1b = WallT + (size_t)((w * 2 + 1) * 16 + l15) * 256 + quad * 8;
    const short* w2  = WallT + (size_t)(128 + w * 64 + l15) * 256 + quad * 8;

    for (int kk = 0; kk < 8; ++kk) {
        s16x8 b0 = *(const s16x8*)(w1a + kk * 32);
        s16x8 b1 = *(const s16x8*)(w1b + kk * 32);
        s16x8 a0 = *(const s16x8*)(w2 + kk * 32);
        s16x8 a1 = *(const s16x8*)(w2 + 16 * 256 + kk * 32);
        s16x8 a2 = *(const s16x8*)(w2 + 32 * 256 + kk * 32);
        s16x8 a3 = *(const s16x8*)(w2 + 48 * 256 + kk * 32);
        acc[0] = __builtin_amdgcn_mfma_f32_16x16x32_bf16(xf[kk], b0, acc[0], 0, 0, 0);
        acc[1] = __builtin_amdgcn_mfma_f32_16x16x32_bf16(xf[kk], b1, acc[1], 0, 0, 0);
        acc[2] = __builtin_amdgcn_mfma_f32_16x16x32_bf16(a0, xf[kk], acc[2], 0, 0, 0);
        acc[3] = __builtin_amdgcn_mfma_f32_16x16x32_bf16(a1, xf[kk], acc[3], 0, 0, 0);
        acc[4] = __builtin_amdgcn_mfma_f32_16x16x32_bf16(a2, xf[kk], acc[4], 0, 0, 0);
        acc[5] = __builtin_amdgcn_mfma_f32_16x16x32_bf16(a3, xf[kk], acc[5], 0, 0, 0);
    }

    // GEMM1 stores: waves 0,1 -> f -> Kp ; waves 2,3 -> g -> Qp
    for (int i = 0; i < 2; ++i) {
        int n = (w * 2 + i) * 16 + l15;
        float bias = (n < 64) ? bfv[n] : bgv[n - 64];
        for (int r = 0; r < 4; ++r) {
            int p = p0 + quad * 4 + r;           // global pixel (b*4096+np)
            short v = f2bf(acc[i][r] + bias);
            if (n < 64) Kp[(size_t)p * 64 + n] = v;
            else        Qp[(size_t)p * 64 + (n - 64)] = v;
        }
    }
    // GEMM2 stores -> Vp panels
    {
        int p     = p0 + l15;
        int bt    = p >> 12, npix = p & 4095;
        int panel = npix >> 6, klo = npix & 63;
        for (int mt = 0; mt < 4; ++mt) {
            for (int r = 0; r < 4; ++r) {
                int c = w * 64 + mt * 16 + quad * 4 + r;
                Vp[((size_t)(bt * 64 + panel) * 256 + c) * 64 + klo] =
                    f2bf(acc[2 + mt][r] + bhv[c]);
            }
        }
    }
}

// ---------------------------------------------------------------------------
// Kernel 3: barrier-free fused attention. Grid 1024 x 128 (2 indep waves).
// Wave = 32 q x 64 ch (QK duplicated x4 across ch-quarters -- cheap).
// 2048 waves = 8/CU = 2/SIMD. bx&7 -> (b, ch-half) XCD swizzle: per-XCD L2
// working set = Kp_b + Qp_b + Vp ch-half ~ 3 MB < 4 MB.
// Per 64-key iter: issue V(it) loads, prefetch K(it+1) (issued AFTER V so
// waiting on V never drains K; K double-buffered via unroll-by-2), QK from
// in-reg K, p=exp(s) (m=0 safe: |s|<~46), P->per-wave LDS slice->A-frags,
// PV. No __syncthreads anywhere.
// ---------------------------------------------------------------------------
#define PST 66

__global__ __launch_bounds__(128, 2) void attn_kernel(
    const short* __restrict__ Kp, const short* __restrict__ Qp,
    const short* __restrict__ Vp, const float* __restrict__ xin,
    const float* __restrict__ scale_p, float* __restrict__ out)
{
    __shared__ short Plds[64 * PST];   // 8.4 KB, rows [w*32+q] per-wave private

    const int tid  = threadIdx.x;
    const int lane = tid & 63, w = tid >> 6;
    const int l31  = lane & 31, g = lane >> 5;
    const int bx   = blockIdx.x;
    const int slot = bx & 7;              // XCD slot
    const int j    = bx >> 3;             // 0..127
    const int b      = slot >> 1;
    const int chqHi  = slot & 1;
    const int chqLo  = j & 1;
    const int qb     = j >> 1;            // 0..63
    const int ch0    = (chqHi * 2 + chqLo) * 64;
    const int q0     = qb * 64 + w * 32;

    // persistent Q B-frags: B[k=d=kc*16+g*8+j][n=q=l31]
    s16x8 Qf[4];
    {
        const short* qp = Qp + (size_t)(b * 4096 + q0 + l31) * 64 + g * 8;
#pragma unroll
        for (int kc = 0; kc < 4; ++kc) Qf[kc] = *(const s16x8*)(qp + kc * 16);
    }

    f32x16 zac;
#pragma unroll
    for (int i = 0; i < 16; ++i) zac[i] = 0.f;
    f32x16 oacc[2];
    oacc[0] = zac; oacc[1] = zac;
    float lsum = 0.f;

    const short* kbase = Kp + (size_t)b * 4096 * 64;
    const short* vbase = Vp + (size_t)b * 64 * 16384 + (size_t)ch0 * 64;
    short* prow = Plds + (w * 32 + l31) * PST;

    // preload K tile 0 (A-frags: A[m=key=kt*32+l31][k=d])
    s16x8 Ka[2][4], Kb[2][4];
    {
        const short* kp = kbase + (size_t)l31 * 64 + g * 8;
#pragma unroll
        for (int kt = 0; kt < 2; ++kt)
#pragma unroll
            for (int kc = 0; kc < 4; ++kc)
                Ka[kt][kc] = *(const s16x8*)(kp + (size_t)kt * 32 * 64 + kc * 16);
    }

    auto body = [&](int it, s16x8 (&KC)[2][4], s16x8 (&KN)[2][4]) {
        // V(it) loads FIRST (vmcnt: waiting on these won't drain K prefetch)
        const short* vt = vbase + (size_t)it * 16384 + (size_t)l31 * 64 + g * 8;
        s16x8 Vf[2][4];
#pragma unroll
        for (int kc = 0; kc < 4; ++kc) {
            Vf[0][kc] = *(const s16x8*)(vt + kc * 16);
            Vf[1][kc] = *(const s16x8*)(vt + 32 * 64 + kc * 16);
        }
        // K(it+1) prefetch
        if (it < 63) {
            const short* kp = kbase + (size_t)(it + 1) * 64 * 64 + (size_t)l31 * 64 + g * 8;
#pragma unroll
            for (int kt = 0; kt < 2; ++kt)
#pragma unroll
                for (int kc = 0; kc < 4; ++kc)
                    KN[kt][kc] = *(const s16x8*)(kp + (size_t)kt * 32 * 64 + kc * 16);
        }

        // S^T[key][q] = K * Q^T  (K already in registers: no memory wait)
        f32x16 st0 = zac, st1 = zac;
#pragma unroll
        for (int kc = 0; kc < 4; ++kc) {
            st0 = __builtin_amdgcn_mfma_f32_32x32x16_bf16(KC[0][kc], Qf[kc], st0, 0, 0, 0);
            st1 = __builtin_amdgcn_mfma_f32_32x32x16_bf16(KC[1][kc], Qf[kc], st1, 0, 0, 0);
        }

        // p = exp(s); C/D: col=q=l31, key = (reg&3)+8*(reg>>2)+4g (+32 for st1)
#pragma unroll
        for (int rg = 0; rg < 4; ++rg) {
            float e0 = __expf(st0[rg * 4 + 0]);
            float e1 = __expf(st0[rg * 4 + 1]);
            float e2 = __expf(st0[rg * 4 + 2]);
            float e3 = __expf(st0[rg * 4 + 3]);
            lsum += (e0 + e1) + (e2 + e3);
            union { __hip_bfloat162 h; short2 s; } u0, u1;
            u0.h = __float22bfloat162_rn(make_float2(e0, e1));
            u1.h = __float22bfloat162_rn(make_float2(e2, e3));
            s16x4 pv = { u0.s.x, u0.s.y, u1.s.x, u1.s.y };
            *(s16x4*)(prow + rg * 8 + g * 4) = pv;
        }
#pragma unroll
        for (int rg = 0; rg < 4; ++rg) {
            float e0 = __expf(st1[rg * 4 + 0]);
            float e1 = __expf(st1[rg * 4 + 1]);
            float e2 = __expf(st1[rg * 4 + 2]);
            float e3 = __expf(st1[rg * 4 + 3]);
            lsum += (e0 + e1) + (e2 + e3);
            union { __hip_bfloat162 h; short2 s; } u0, u1;
            u0.h = __float22bfloat162_rn(make_float2(e0, e1));
            u1.h = __float22bfloat162_rn(make_float2(e2, e3));
            s16x4 pv = { u0.s.x, u0.s.y, u1.s.x, u1.s.y };
            *(s16x4*)(prow + 32 + rg * 8 + g * 4) = pv;
        }

        // P A-frags (same-wave LDS: lgkmcnt ordering, no barrier)
        s16x8 Pf[4];
#pragma unroll
        for (int kc = 0; kc < 4; ++kc)
            Pf[kc] = *(const s16x8*)(prow + kc * 16 + g * 8);

        // O += P V  (waits only on V(it): vmcnt leaves K(it+1) in flight)
#pragma unroll
        for (int kc = 0; kc < 4; ++kc) {
            oacc[0] = __builtin_amdgcn_mfma_f32_32x32x16_bf16(Pf[kc], Vf[0][kc], oacc[0], 0, 0, 0);
            oacc[1] = __builtin_amdgcn_mfma_f32_32x32x16_bf16(Pf[kc], Vf[1][kc], oacc[1], 0, 0, 0);
        }
    };

    for (int it = 0; it < 64; it += 2) {
        body(it,     Ka, Kb);
        body(it + 1, Kb, Ka);
    }

    // l: combine g-halves (lanes l and l+32 hold same q=l31)
    lsum += __shfl_xor(lsum, 32, 64);

    const float scale = *scale_p;
#pragma unroll
    for (int reg = 0; reg < 16; ++reg) {
        const int qr = (reg & 3) + 8 * (reg >> 2) + 4 * g;   // q-row within 32
        const float lq = __shfl(lsum, qr, 64);
        const float linv = 1.f / lq;
        const int q = q0 + qr;
#pragma unroll
        for (int ct = 0; ct < 2; ++ct) {
            size_t idx = (size_t)(b * 4096 + q) * 256 + ch0 + ct * 32 + l31;
            out[idx] = scale * (oacc[ct][reg] * linv) + xin[idx];
        }
    }
}

// ---------------------------------------------------------------------------
extern "C" void kernel_launch(void* const* d_in, const int* in_sizes, int n_in,
                              void* d_out, int out_size, void* d_ws, size_t ws_size,
                              hipStream_t stream) {
    (void)in_sizes; (void)n_in; (void)out_size; (void)ws_size;
    const float* x     = (const float*)d_in[0];
    const float* Wf    = (const float*)d_in[1];
    const float* bfv   = (const float*)d_in[2];
    const float* Wg    = (const float*)d_in[3];
    const float* bgv   = (const float*)d_in[4];
    const float* Wh    = (const float*)d_in[5];
    const float* bhv   = (const float*)d_in[6];
    const float* scale = (const float*)d_in[7];
    float* out = (float*)d_out;

    short* WallT = (short*)d_ws;                      // 384*256
    short* Kp    = WallT + 384 * 256;                 // 4*4096*64
    short* Qp    = Kp + (size_t)4 * 4096 * 64;        // 4*4096*64
    short* Vp    = Qp + (size_t)4 * 4096 * 64;        // 4*64*256*64

    wconv_kernel<<<384, 256, 0, stream>>>(Wf, Wg, Wh, WallT);
    proj_kernel<<<1024, 256, 0, stream>>>(x, WallT, bfv, bgv, bhv, Kp, Qp, Vp);
    attn_kernel<<<1024, 128, 0, stream>>>(Kp, Qp, Vp, x, scale, out);
}

// Round 7
// 269.558 us; speedup vs baseline: 1.2762x; 1.2762x over previous
//
#include <hip/hip_runtime.h>
#include <hip/hip_bf16.h>
#include <math.h>

typedef float f32x4  __attribute__((ext_vector_type(4)));
typedef float f32x16 __attribute__((ext_vector_type(16)));
typedef short s16x8  __attribute__((ext_vector_type(8)));
typedef short s16x4  __attribute__((ext_vector_type(4)));

__device__ inline short f2bf(float f) {
    union { __hip_bfloat16 h; short s; } u;
    u.h = __float2bfloat16(f);
    return u.s;
}

__device__ inline s16x8 f32x8_to_bf16x8(f32x4 a, f32x4 b) {
    s16x8 o;
    union { __hip_bfloat162 h; short2 s; } u;
    u.h = __float22bfloat162_rn(make_float2(a[0], a[1])); o[0] = u.s.x; o[1] = u.s.y;
    u.h = __float22bfloat162_rn(make_float2(a[2], a[3])); o[2] = u.s.x; o[3] = u.s.y;
    u.h = __float22bfloat162_rn(make_float2(b[0], b[1])); o[4] = u.s.x; o[5] = u.s.y;
    u.h = __float22bfloat162_rn(make_float2(b[2], b[3])); o[6] = u.s.x; o[7] = u.s.y;
    return o;
}

// ---------------------------------------------------------------------------
// Kernel 1: pack weights -> WallT[n][k] bf16, n in [0,384) = f|g|h cols
// ---------------------------------------------------------------------------
__global__ __launch_bounds__(256) void wconv_kernel(
    const float* __restrict__ Wf, const float* __restrict__ Wg,
    const float* __restrict__ Wh, short* __restrict__ WallT)
{
    int t = blockIdx.x * 256 + threadIdx.x;
    int n = t >> 8;
    int k = t & 255;
    float v;
    if (n < 64)       v = Wf[k * 64 + n];
    else if (n < 128) v = Wg[k * 64 + (n - 64)];
    else              v = Wh[k * 256 + (n - 128)];
    WallT[n * 256 + k] = f2bf(v);
}

// ---------------------------------------------------------------------------
// Kernel 2: projections (unchanged from R6 to isolate attn delta).
//   Kp[b][key][64], Qp[b][q][64], Vp[b][panel=key>>6][ch][key&63]
// ---------------------------------------------------------------------------
__global__ __launch_bounds__(256) void proj_kernel(
    const float* __restrict__ x, const short* __restrict__ WallT,
    const float* __restrict__ bfv, const float* __restrict__ bgv,
    const float* __restrict__ bhv,
    short* __restrict__ Kp, short* __restrict__ Qp, short* __restrict__ Vp)
{
    const int tid  = threadIdx.x;
    const int lane = tid & 63, w = tid >> 6;
    const int quad = lane >> 4, l15 = lane & 15;
    const int p0 = blockIdx.x * 16;

    s16x8 xf[8];
    {
        const float* xrow = x + (size_t)(p0 + l15) * 256 + quad * 8;
        for (int kk = 0; kk < 8; ++kk) {
            f32x4 a = *(const f32x4*)(xrow + kk * 32);
            f32x4 c = *(const f32x4*)(xrow + kk * 32 + 4);
            xf[kk] = f32x8_to_bf16x8(a, c);
        }
    }

    f32x4 acc[6];
    const f32x4 zac = {0.f, 0.f, 0.f, 0.f};
    for (int i = 0; i < 6; ++i) acc[i] = zac;

    const short* w1a = WallT + (size_t)((w * 2 + 0) * 16 + l15) * 256 + quad * 8;
    const short* w1b = WallT + (size_t)((w * 2 + 1) * 16 + l15) * 256 + quad * 8;
    const short* w2  = WallT + (size_t)(128 + w * 64 + l15) * 256 + quad * 8;

    for (int kk = 0; kk < 8; ++kk) {
        s16x8 b0 = *(const s16x8*)(w1a + kk * 32);
        s16x8 b1 = *(const s16x8*)(w1b + kk * 32);
        s16x8 a0 = *(const s16x8*)(w2 + kk * 32);
        s16x8 a1 = *(const s16x8*)(w2 + 16 * 256 + kk * 32);
        s16x8 a2 = *(const s16x8*)(w2 + 32 * 256 + kk * 32);
        s16x8 a3 = *(const s16x8*)(w2 + 48 * 256 + kk * 32);
        acc[0] = __builtin_amdgcn_mfma_f32_16x16x32_bf16(xf[kk], b0, acc[0], 0, 0, 0);
        acc[1] = __builtin_amdgcn_mfma_f32_16x16x32_bf16(xf[kk], b1, acc[1], 0, 0, 0);
        acc[2] = __builtin_amdgcn_mfma_f32_16x16x32_bf16(a0, xf[kk], acc[2], 0, 0, 0);
        acc[3] = __builtin_amdgcn_mfma_f32_16x16x32_bf16(a1, xf[kk], acc[3], 0, 0, 0);
        acc[4] = __builtin_amdgcn_mfma_f32_16x16x32_bf16(a2, xf[kk], acc[4], 0, 0, 0);
        acc[5] = __builtin_amdgcn_mfma_f32_16x16x32_bf16(a3, xf[kk], acc[5], 0, 0, 0);
    }

    for (int i = 0; i < 2; ++i) {
        int n = (w * 2 + i) * 16 + l15;
        float bias = (n < 64) ? bfv[n] : bgv[n - 64];
        for (int r = 0; r < 4; ++r) {
            int p = p0 + quad * 4 + r;
            short v = f2bf(acc[i][r] + bias);
            if (n < 64) Kp[(size_t)p * 64 + n] = v;
            else        Qp[(size_t)p * 64 + (n - 64)] = v;
        }
    }
    {
        int p     = p0 + l15;
        int bt    = p >> 12, npix = p & 4095;
        int panel = npix >> 6, klo = npix & 63;
        for (int mt = 0; mt < 4; ++mt) {
            for (int r = 0; r < 4; ++r) {
                int c = w * 64 + mt * 16 + quad * 4 + r;
                Vp[((size_t)(bt * 64 + panel) * 256 + c) * 64 + klo] =
                    f2bf(acc[2 + mt][r] + bhv[c]);
            }
        }
    }
}

// ---------------------------------------------------------------------------
// Kernel 3: fused attention, m97-style LDS-staged structure.
// Grid 512 x 256 thr (4 waves), __launch_bounds__(256,3) -> 3 blocks/CU =
// 12 waves/CU. Block = 64 q x 128 ch (ch-split x2 across blocks); wave
// (w>>1 = q-half, w&1 = ch-half) = 32q x 64ch, 32x32x16 MFMAs.
// Per 64-key iter: K(it) A-frags direct from L2 (issued FIRST -> QK's
// vmcnt drain never waits on V), V(it+1) -> regs, QK, p=exp(s) (m=0 safe:
// |s| <= ~48 < 88), P -> per-wave LDS slice -> A-frags, PV from Vlds;
// barrier / commit V(it+1) / barrier.  bx&7 -> (b,chh) XCD-L2 swizzle.
// ---------------------------------------------------------------------------
#define VST 72
#define PST 72

__global__ __launch_bounds__(256, 3) void attn_kernel(
    const short* __restrict__ Kp, const short* __restrict__ Qp,
    const short* __restrict__ Vp, const float* __restrict__ xin,
    const float* __restrict__ scale_p, float* __restrict__ out)
{
    __shared__ short Vlds[128 * VST];   // 18.4 KB: V^T ch-half [128][64keys]
    __shared__ short Plds[128 * PST];   // 18.4 KB: 4 waves x 32 q-rows

    const int tid  = threadIdx.x;
    const int lane = tid & 63, w = tid >> 6;
    const int l31  = lane & 31, g = lane >> 5;
    const int bx   = blockIdx.x;
    const int slot = bx & 7;
    const int b    = slot >> 1;
    const int chh  = slot & 1;
    const int qt   = bx >> 3;                 // 0..63
    const int q0   = qt * 64 + (w >> 1) * 32;
    const int ct0  = (w & 1) * 2;             // ch-tile base (2 tiles of 32) in the half

    // persistent Q B-frags: B[k=d=kc*16+g*8+j][n=q=l31]
    s16x8 Qf[4];
    {
        const short* qp = Qp + (size_t)(b * 4096 + q0 + l31) * 64 + g * 8;
#pragma unroll
        for (int kc = 0; kc < 4; ++kc) Qf[kc] = *(const s16x8*)(qp + kc * 16);
    }

    f32x16 zac;
#pragma unroll
    for (int i = 0; i < 16; ++i) zac[i] = 0.f;
    f32x16 oacc[2];
    oacc[0] = zac; oacc[1] = zac;
    float lsum = 0.f;

    const short* kbase = Kp + (size_t)b * 4096 * 64;
    const short* vsrc  = Vp + ((size_t)(b * 64) * 256 + chh * 128) * 64;  // + it*16384

    // V staging role: thread t -> row sr (=ch in half), 32-short half sh
    const int sr = tid >> 1, sh = tid & 1;
    const short* vsl = vsrc + (size_t)sr * 64 + sh * 32;
    short*       vdl = Vlds + sr * VST + sh * 32;

    // stage V(0)
    {
        s16x8 t0 = *(const s16x8*)(vsl);
        s16x8 t1 = *(const s16x8*)(vsl + 8);
        s16x8 t2 = *(const s16x8*)(vsl + 16);
        s16x8 t3 = *(const s16x8*)(vsl + 24);
        *(s16x8*)(vdl)      = t0;
        *(s16x8*)(vdl + 8)  = t1;
        *(s16x8*)(vdl + 16) = t2;
        *(s16x8*)(vdl + 24) = t3;
    }
    __syncthreads();

    short* prow = Plds + (w * 32 + l31) * PST;
    const short* vrow0 = Vlds + (ct0 * 32 + l31) * VST;
    const short* vrow1 = Vlds + ((ct0 + 1) * 32 + l31) * VST;

    for (int it = 0; it < 64; ++it) {
        // K(it) A-frags: A[m=key=kt*32+l31][k=d]  (issued first!)
        s16x8 Kf[2][4];
        {
            const short* kp = kbase + (size_t)(it * 64 + l31) * 64 + g * 8;
#pragma unroll
            for (int kt = 0; kt < 2; ++kt)
#pragma unroll
                for (int kc = 0; kc < 4; ++kc)
                    Kf[kt][kc] = *(const s16x8*)(kp + (size_t)kt * 32 * 64 + kc * 16);
        }
        // V(it+1) -> regs (committed after barrier at loop end)
        s16x8 vt0, vt1, vt2, vt3;
        if (it < 63) {
            const short* vs = vsl + (size_t)(it + 1) * 16384;
            vt0 = *(const s16x8*)(vs);
            vt1 = *(const s16x8*)(vs + 8);
            vt2 = *(const s16x8*)(vs + 16);
            vt3 = *(const s16x8*)(vs + 24);
        }

        // S^T[key][q] = K * Q^T
        f32x16 st0 = zac, st1 = zac;
#pragma unroll
        for (int kc = 0; kc < 4; ++kc) {
            st0 = __builtin_amdgcn_mfma_f32_32x32x16_bf16(Kf[0][kc], Qf[kc], st0, 0, 0, 0);
            st1 = __builtin_amdgcn_mfma_f32_32x32x16_bf16(Kf[1][kc], Qf[kc], st1, 0, 0, 0);
        }

        // p = exp(s); C/D: col=q=l31, key = (reg&3)+8*(reg>>2)+4g (+32 for st1)
#pragma unroll
        for (int rg = 0; rg < 4; ++rg) {
            float e0 = __expf(st0[rg * 4 + 0]);
            float e1 = __expf(st0[rg * 4 + 1]);
            float e2 = __expf(st0[rg * 4 + 2]);
            float e3 = __expf(st0[rg * 4 + 3]);
            lsum += (e0 + e1) + (e2 + e3);
            union { __hip_bfloat162 h; short2 s; } u0, u1;
            u0.h = __float22bfloat162_rn(make_float2(e0, e1));
            u1.h = __float22bfloat162_rn(make_float2(e2, e3));
            s16x4 pv = { u0.s.x, u0.s.y, u1.s.x, u1.s.y };
            *(s16x4*)(prow + rg * 8 + g * 4) = pv;
        }
#pragma unroll
        for (int rg = 0; rg < 4; ++rg) {
            float e0 = __expf(st1[rg * 4 + 0]);
            float e1 = __expf(st1[rg * 4 + 1]);
            float e2 = __expf(st1[rg * 4 + 2]);
            float e3 = __expf(st1[rg * 4 + 3]);
            lsum += (e0 + e1) + (e2 + e3);
            union { __hip_bfloat162 h; short2 s; } u0, u1;
            u0.h = __float22bfloat162_rn(make_float2(e0, e1));
            u1.h = __float22bfloat162_rn(make_float2(e2, e3));
            s16x4 pv = { u0.s.x, u0.s.y, u1.s.x, u1.s.y };
            *(s16x4*)(prow + 32 + rg * 8 + g * 4) = pv;
        }

        // P A-frags (same-wave LDS ordering; no barrier needed)
        s16x8 Pf[4];
#pragma unroll
        for (int kc = 0; kc < 4; ++kc)
            Pf[kc] = *(const s16x8*)(prow + kc * 16 + g * 8);

        // O += P V: B[k=key][n=ch=l31] from Vlds rows (ct*32+l31)
#pragma unroll
        for (int kc = 0; kc < 4; ++kc) {
            s16x8 vb0 = *(const s16x8*)(vrow0 + kc * 16 + g * 8);
            s16x8 vb1 = *(const s16x8*)(vrow1 + kc * 16 + g * 8);
            oacc[0] = __builtin_amdgcn_mfma_f32_32x32x16_bf16(Pf[kc], vb0, oacc[0], 0, 0, 0);
            oacc[1] = __builtin_amdgcn_mfma_f32_32x32x16_bf16(Pf[kc], vb1, oacc[1], 0, 0, 0);
        }

        __syncthreads();                      // all waves done with Vlds(it)
        if (it < 63) {
            *(s16x8*)(vdl)      = vt0;
            *(s16x8*)(vdl + 8)  = vt1;
            *(s16x8*)(vdl + 16) = vt2;
            *(s16x8*)(vdl + 24) = vt3;
        }
        __syncthreads();                      // commit visible before next PV
    }

    // l: combine g-halves (lanes l and l+32 hold same q=l31)
    lsum += __shfl_xor(lsum, 32, 64);

    const float scale = *scale_p;
#pragma unroll
    for (int reg = 0; reg < 16; ++reg) {
        const int qr = (reg & 3) + 8 * (reg >> 2) + 4 * g;   // q-row within 32
        const float lq = __shfl(lsum, qr, 64);
        const float linv = 1.f / lq;
        const int q = q0 + qr;
#pragma unroll
        for (int ct = 0; ct < 2; ++ct) {
            size_t idx = (size_t)(b * 4096 + q) * 256 + chh * 128 + (ct0 + ct) * 32 + l31;
            out[idx] = scale * (oacc[ct][reg] * linv) + xin[idx];
        }
    }
}

// ---------------------------------------------------------------------------
extern "C" void kernel_launch(void* const* d_in, const int* in_sizes, int n_in,
                              void* d_out, int out_size, void* d_ws, size_t ws_size,
                              hipStream_t stream) {
    (void)in_sizes; (void)n_in; (void)out_size; (void)ws_size;
    const float* x     = (const float*)d_in[0];
    const float* Wf    = (const float*)d_in[1];
    const float* bfv   = (const float*)d_in[2];
    const float* Wg    = (const float*)d_in[3];
    const float* bgv   = (const float*)d_in[4];
    const float* Wh    = (const float*)d_in[5];
    const float* bhv   = (const float*)d_in[6];
    const float* scale = (const float*)d_in[7];
    float* out = (float*)d_out;

    short* WallT = (short*)d_ws;                      // 384*256
    short* Kp    = WallT + 384 * 256;                 // 4*4096*64
    short* Qp    = Kp + (size_t)4 * 4096 * 64;        // 4*4096*64
    short* Vp    = Qp + (size_t)4 * 4096 * 64;        // 4*64*256*64

    wconv_kernel<<<384, 256, 0, stream>>>(Wf, Wg, Wh, WallT);
    proj_kernel<<<1024, 256, 0, stream>>>(x, WallT, bfv, bgv, bhv, Kp, Qp, Vp);
    attn_kernel<<<512, 256, 0, stream>>>(Kp, Qp, Vp, x, scale, out);
}